// Round 9
// baseline (220.109 us; speedup 1.0000x reference)
//
#include <hip/hip_runtime.h>
#include <math.h>

#define F 1024
#define BM 128
#define BN 128
#define BK 16

typedef _Float16 h2 __attribute__((ext_vector_type(2)));
typedef _Float16 h4 __attribute__((ext_vector_type(4)));
typedef _Float16 h8 __attribute__((ext_vector_type(8)));
typedef float v4f __attribute__((ext_vector_type(4)));

#define SHUF2(v, i, j) __builtin_shufflevector(v, v, i, j)
#define SHUF4(v, a, b, c, d) __builtin_shufflevector(v, v, a, b, c, d)

// VOP3P with op_sel broadcast — syntax bench-proven in R5/R8.
static __device__ __forceinline__ h2 pk_add_blo(h2 a, h2 b) {
  h2 d;
  asm("v_pk_add_f16 %0, %1, %2 op_sel:[0,0] op_sel_hi:[0,1]"
      : "=v"(d) : "v"(a), "v"(b));
  return d;
}
static __device__ __forceinline__ h2 pk_add_bhi(h2 a, h2 b) {
  h2 d;
  asm("v_pk_add_f16 %0, %1, %2 op_sel:[1,0] op_sel_hi:[1,1]"
      : "=v"(d) : "v"(a), "v"(b));
  return d;
}
static __device__ __forceinline__ h2 pk_max(h2 a, h2 b) {
  h2 d;
  asm("v_pk_max_f16 %0, %1, %2" : "=v"(d) : "v"(a), "v"(b));
  return d;
}

// ------- LayerNorm (one wave per row) + fused W f32->fp16 convert -------
// Block b: waves handle rows 4b..4b+3 of x; afterwards the block converts
// W row b (1024 floats) to fp16. Independent work, no extra sync needed.
__global__ __launch_bounds__(256) void ln_cvt_kernel(const float* __restrict__ x,
                                                     const float* __restrict__ gamma,
                                                     const float* __restrict__ beta,
                                                     const float* __restrict__ Wm,
                                                     _Float16* __restrict__ xnh,
                                                     _Float16* __restrict__ Wh) {
  const int lane = threadIdx.x & 63;
  const int wv = threadIdx.x >> 6;
  const int row = blockIdx.x * 4 + wv;
  const float4* xr = (const float4*)(x + (size_t)row * F);
  float4 v[4];
  float s = 0.f;
#pragma unroll
  for (int j = 0; j < 4; ++j) {
    v[j] = xr[lane + 64 * j];
    s += v[j].x + v[j].y + v[j].z + v[j].w;
  }
#pragma unroll
  for (int off = 32; off; off >>= 1) s += __shfl_xor(s, off, 64);
  const float mu = s * (1.0f / F);
  float sq = 0.f;
#pragma unroll
  for (int j = 0; j < 4; ++j) {
    v[j].x -= mu; v[j].y -= mu; v[j].z -= mu; v[j].w -= mu;
    sq += v[j].x * v[j].x + v[j].y * v[j].y + v[j].z * v[j].z + v[j].w * v[j].w;
  }
#pragma unroll
  for (int off = 32; off; off >>= 1) sq += __shfl_xor(sq, off, 64);
  const float r = rsqrtf(sq * (1.0f / F) + 1e-5f);
  const float4* g4 = (const float4*)gamma;
  const float4* b4 = (const float4*)beta;
  h4* o = (h4*)(xnh + (size_t)row * F);
#pragma unroll
  for (int j = 0; j < 4; ++j) {
    const int idx = lane + 64 * j;
    const float4 g = g4[idx];
    const float4 bb = b4[idx];
    h4 ov = {(_Float16)(v[j].x * r * g.x + bb.x),
             (_Float16)(v[j].y * r * g.y + bb.y),
             (_Float16)(v[j].z * r * g.z + bb.z),
             (_Float16)(v[j].w * r * g.w + bb.w)};
    o[idx] = ov;
  }
  // fused: convert W row blockIdx.x (1024 f32) -> fp16
  {
    const int i = (int)blockIdx.x * 256 + threadIdx.x;  // float4 index into W
    const v4f wv4 = ((const v4f*)Wm)[i];
    h4 wo = {(_Float16)wv4.x, (_Float16)wv4.y, (_Float16)wv4.z, (_Float16)wv4.w};
    ((h4*)Wh)[i] = wo;
  }
}

// ---------------- fp16 tropical (max,+) GEMM, split-K, LDS double-buffer ----------------
// One __syncthreads per k-tile: compute buf[kt&1], write prefetch to buf[kt+1&1].
__global__ __launch_bounds__(256) void trop_h(const _Float16* __restrict__ A,
                                              const _Float16* __restrict__ Wh,
                                              const float* __restrict__ bias,
                                              _Float16* __restrict__ dsth,
                                              float* __restrict__ outf,
                                              int ntiles, int totrows, int fuse) {
  __shared__ _Float16 As[2][BM][BK + 4];  // 2 x 5120 B
  __shared__ _Float16 Bs[2][BK][BN];      // 2 x 4096 B

  const int tid = threadIdx.x;
  const int tx = tid & 15;
  const int ty = tid >> 4;
  const int row0 = blockIdx.y * BM;
  const int col0 = blockIdx.x * BN;
  const int kbase = blockIdx.z * ntiles * BK;

  const int am2 = tid >> 1, aj = tid & 1;
  const int bi = tid >> 4, bj = tid & 15;

  const _Float16* Asrc = A + (size_t)(row0 + am2) * F + kbase + aj * 8;
  const _Float16* Bsrc = Wh + (size_t)(kbase + bi) * F + col0 + bj * 8;

  const _Float16 NEG = (_Float16)(-60000.0f);
  h2 acc[8][4];
#pragma unroll
  for (int m = 0; m < 8; ++m)
#pragma unroll
    for (int np = 0; np < 4; ++np) acc[m][np] = (h2){NEG, NEG};

  // stage tile 0 into buf 0
  {
    h8 a_st = *(const h8*)Asrc;
    h8 b_st = *(const h8*)Bsrc;
    *(h4*)&As[0][am2][aj * 8] = SHUF4(a_st, 0, 1, 2, 3);
    *(h4*)&As[0][am2][aj * 8 + 4] = SHUF4(a_st, 4, 5, 6, 7);
    *(h8*)&Bs[0][bi][bj * 8] = b_st;
  }
  __syncthreads();

  for (int kt = 0; kt < ntiles; ++kt) {
    const int cur = kt & 1;
    h8 a_st, b_st;
    if (kt + 1 < ntiles) {
      a_st = *(const h8*)(Asrc + (kt + 1) * BK);
      b_st = *(const h8*)(Bsrc + (size_t)(kt + 1) * BK * F);
    }

#pragma unroll
    for (int kq = 0; kq < 4; ++kq) {
      h4 a4[8];
#pragma unroll
      for (int m = 0; m < 8; ++m) a4[m] = *(const h4*)&As[cur][ty * 8 + m][kq * 4];
#pragma unroll
      for (int kp = 0; kp < 2; ++kp) {
        const int k = kq * 4 + kp * 2;
        const h8 bA = *(const h8*)&Bs[cur][k][tx * 8];
        const h8 bB = *(const h8*)&Bs[cur][k + 1][tx * 8];
        h2 b0[4], b1[4];
        b0[0] = SHUF2(bA, 0, 1); b0[1] = SHUF2(bA, 2, 3);
        b0[2] = SHUF2(bA, 4, 5); b0[3] = SHUF2(bA, 6, 7);
        b1[0] = SHUF2(bB, 0, 1); b1[1] = SHUF2(bB, 2, 3);
        b1[2] = SHUF2(bB, 4, 5); b1[3] = SHUF2(bB, 6, 7);
#pragma unroll
        for (int m = 0; m < 8; ++m) {
          const h2 a = kp ? SHUF2(a4[m], 2, 3) : SHUF2(a4[m], 0, 1);
#pragma unroll
          for (int np = 0; np < 4; ++np) {
            const h2 s0 = pk_add_blo(a, b0[np]);  // a_k  + {b_k(n), b_k(n1)}
            const h2 s1 = pk_add_bhi(a, b1[np]);  // a_k1 + {b_k1(n), b_k1(n1)}
            acc[m][np] = pk_max(acc[m][np], pk_max(s0, s1));
          }
        }
      }
    }

    if (kt + 1 < ntiles) {
      const int nxt = cur ^ 1;
      *(h4*)&As[nxt][am2][aj * 8] = SHUF4(a_st, 0, 1, 2, 3);
      *(h4*)&As[nxt][am2][aj * 8 + 4] = SHUF4(a_st, 4, 5, 6, 7);
      *(h8*)&Bs[nxt][bi][bj * 8] = b_st;
      __syncthreads();
    }
  }

  if (fuse) {
    const float4 bv0 = *(const float4*)(bias + col0 + tx * 8);
    const float4 bv1 = *(const float4*)(bias + col0 + tx * 8 + 4);
#pragma unroll
    for (int m = 0; m < 8; ++m) {
      float* orow = outf + (size_t)(row0 + ty * 8 + m) * F + col0 + tx * 8;
      float4 o0, o1;
      o0.x = fmaxf((float)acc[m][0].x, bv0.x);
      o0.y = fmaxf((float)acc[m][0].y, bv0.y);
      o0.z = fmaxf((float)acc[m][1].x, bv0.z);
      o0.w = fmaxf((float)acc[m][1].y, bv0.w);
      o1.x = fmaxf((float)acc[m][2].x, bv1.x);
      o1.y = fmaxf((float)acc[m][2].y, bv1.y);
      o1.z = fmaxf((float)acc[m][3].x, bv1.z);
      o1.w = fmaxf((float)acc[m][3].y, bv1.w);
      *(float4*)orow = o0;
      *(float4*)(orow + 4) = o1;
    }
  } else {
    _Float16* base = dsth + (size_t)blockIdx.z * totrows * F;
#pragma unroll
    for (int m = 0; m < 8; ++m) {
      h8 ov = {acc[m][0].x, acc[m][0].y, acc[m][1].x, acc[m][1].y,
               acc[m][2].x, acc[m][2].y, acc[m][3].x, acc[m][3].y};
      *(h8*)(base + (size_t)(row0 + ty * 8 + m) * F + col0 + tx * 8) = ov;
    }
  }
}

// ---------------- combine: out = max(NP fp16 partials, bias) in f32 ----------------
template <int NP>
__global__ __launch_bounds__(256) void combineNh(const _Float16* __restrict__ p,
                                                 size_t plane,
                                                 const float* __restrict__ bias,
                                                 float* __restrict__ out) {
  const int i = blockIdx.x * 256 + threadIdx.x;  // h8 index
  h8 v = ((const h8*)p)[i];
  h2* vv = (h2*)&v;
#pragma unroll
  for (int q = 1; q < NP; ++q) {
    const h8 u = ((const h8*)(p + (size_t)q * plane))[i];
    const h2* uu = (const h2*)&u;
#pragma unroll
    for (int j = 0; j < 4; ++j) vv[j] = pk_max(vv[j], uu[j]);
  }
  const int nb = (i & (F / 8 - 1)) * 8;
  const v4f bb0 = *(const v4f*)(bias + nb);
  const v4f bb1 = *(const v4f*)(bias + nb + 4);
  float4* o4 = (float4*)(out + (size_t)i * 8);
  float4 o0, o1;
  o0.x = fmaxf((float)v[0], bb0.x);
  o0.y = fmaxf((float)v[1], bb0.y);
  o0.z = fmaxf((float)v[2], bb0.z);
  o0.w = fmaxf((float)v[3], bb0.w);
  o1.x = fmaxf((float)v[4], bb1.x);
  o1.y = fmaxf((float)v[5], bb1.y);
  o1.z = fmaxf((float)v[6], bb1.z);
  o1.w = fmaxf((float)v[7], bb1.w);
  o4[0] = o0;
  o4[1] = o1;
}

extern "C" void kernel_launch(void* const* d_in, const int* in_sizes, int n_in,
                              void* d_out, int out_size, void* d_ws, size_t ws_size,
                              hipStream_t stream) {
  const float* x = (const float*)d_in[0];
  const float* Wm = (const float*)d_in[1];
  const float* bias = (const float*)d_in[2];
  const float* gamma = (const float*)d_in[3];
  const float* beta = (const float*)d_in[4];
  float* out = (float*)d_out;

  const int Brows = in_sizes[0] / F;  // 4096
  const size_t plane = (size_t)Brows * F;

  _Float16* xnh = (_Float16*)d_ws;       // plane halves
  _Float16* Wh = xnh + plane;            // F*F halves
  _Float16* parts = Wh + (size_t)F * F;  // up to 4 planes halves

  ln_cvt_kernel<<<Brows / 4, 256, 0, stream>>>(x, gamma, beta, Wm, xnh, Wh);

  const size_t need4 = (5 * plane + (size_t)F * F) * sizeof(_Float16);
  const size_t need1 = (plane + (size_t)F * F) * sizeof(_Float16);
  if (ws_size >= need4) {
    dim3 grid(F / BN, Brows / BM, 4);  // 1024 blocks = 4 blocks/CU
    trop_h<<<grid, 256, 0, stream>>>(xnh, Wh, bias, parts, nullptr,
                                     (F / BK) / 4, Brows, 0);
    combineNh<4><<<(int)(plane / 2048), 256, 0, stream>>>(parts, plane, bias, out);
  } else if (ws_size >= need1) {
    dim3 grid(F / BN, Brows / BM, 1);
    trop_h<<<grid, 256, 0, stream>>>(xnh, Wh, bias, nullptr, out, F / BK, Brows, 1);
  }
}

// Round 10
// 210.272 us; speedup vs baseline: 1.0468x; 1.0468x over previous
//
#include <hip/hip_runtime.h>
#include <math.h>

#define F 1024
#define BM 128
#define BN 128
#define BK 16

typedef _Float16 h2 __attribute__((ext_vector_type(2)));
typedef _Float16 h4 __attribute__((ext_vector_type(4)));
typedef _Float16 h8 __attribute__((ext_vector_type(8)));
typedef float v4f __attribute__((ext_vector_type(4)));

static __device__ __forceinline__ float fmax3(float a, float b, float c) {
  float d;
  asm("v_max3_f32 %0, %1, %2, %3" : "=v"(d) : "v"(a), "v"(b), "v"(c));
  return d;
}
static __device__ __forceinline__ h2 pk_max(h2 a, h2 b) {
  h2 d;
  asm("v_pk_max_f16 %0, %1, %2" : "=v"(d) : "v"(a), "v"(b));
  return d;
}

// ---------------- LayerNorm: one WAVE per row, f32 out (R2-proven) ----------------
__global__ __launch_bounds__(256) void ln_kernel(const float* __restrict__ x,
                                                 const float* __restrict__ gamma,
                                                 const float* __restrict__ beta,
                                                 float* __restrict__ xn) {
  const int lane = threadIdx.x & 63;
  const int wv = threadIdx.x >> 6;
  const int row = blockIdx.x * 4 + wv;
  const float4* xr = (const float4*)(x + (size_t)row * F);
  float4 v[4];
  float s = 0.f;
#pragma unroll
  for (int j = 0; j < 4; ++j) {
    v[j] = xr[lane + 64 * j];
    s += v[j].x + v[j].y + v[j].z + v[j].w;
  }
#pragma unroll
  for (int off = 32; off; off >>= 1) s += __shfl_xor(s, off, 64);
  const float mu = s * (1.0f / F);
  float sq = 0.f;
#pragma unroll
  for (int j = 0; j < 4; ++j) {
    v[j].x -= mu; v[j].y -= mu; v[j].z -= mu; v[j].w -= mu;
    sq += v[j].x * v[j].x + v[j].y * v[j].y + v[j].z * v[j].z + v[j].w * v[j].w;
  }
#pragma unroll
  for (int off = 32; off; off >>= 1) sq += __shfl_xor(sq, off, 64);
  const float r = rsqrtf(sq * (1.0f / F) + 1e-5f);
  const float4* g4 = (const float4*)gamma;
  const float4* b4 = (const float4*)beta;
  float4* o = (float4*)(xn + (size_t)row * F);
#pragma unroll
  for (int j = 0; j < 4; ++j) {
    const int idx = lane + 64 * j;
    const float4 g = g4[idx];
    const float4 bb = b4[idx];
    float4 ov;
    ov.x = v[j].x * r * g.x + bb.x;
    ov.y = v[j].y * r * g.y + bb.y;
    ov.z = v[j].z * r * g.z + bb.z;
    ov.w = v[j].w * r * g.w + bb.w;
    o[idx] = ov;
  }
}

// ---------------- f32 tropical (max,+) GEMM: 3 cyc/update mix ----------------
// Thread (tx,ty): rows 8ty..+7, cols {4tx..+3} u {64+4tx..+3} (2-way-bank map).
// Inner: per k-pair per (m,n): v_add_f32 x2 + v_max3_f32 -> 3 cyc/update.
// fp16 partials for split-K; f32+bias for fused path.
__global__ __launch_bounds__(256, 4) void trop_f(const float* __restrict__ A,
                                                 const float* __restrict__ Wm,
                                                 const float* __restrict__ bias,
                                                 _Float16* __restrict__ dsth,
                                                 float* __restrict__ outf,
                                                 int ntiles, int totrows, int fuse) {
  __shared__ float As[2][BK][BM + 4];  // transposed: As[buf][k][m]
  __shared__ float Bs[2][BK][BN];

  const int tid = threadIdx.x;
  const int tx = tid & 15;
  const int ty = tid >> 4;
  const int row0 = blockIdx.y * BM;
  const int col0 = blockIdx.x * BN;
  const int kbase = blockIdx.z * ntiles * BK;

  const int am = tid >> 2;          // A stage: row am / am+64
  const int ak = (tid & 3) << 2;    // k offset 0,4,8,12
  const int bk = tid >> 5;          // B stage: k-row bk / bk+8
  const int bn = (tid & 31) << 2;   // col offset

  const float* Arow0 = A + (size_t)(row0 + am) * F + kbase + ak;
  const float* Arow1 = A + (size_t)(row0 + am + 64) * F + kbase + ak;
  const float* Wrow0 = Wm + (size_t)(kbase + bk) * F + col0 + bn;
  const float* Wrow1 = Wm + (size_t)(kbase + bk + 8) * F + col0 + bn;

  float acc[8][8];
#pragma unroll
  for (int m = 0; m < 8; ++m)
#pragma unroll
    for (int n = 0; n < 8; ++n) acc[m][n] = -INFINITY;

  // stage tile 0 into buf 0
  {
    const float4 a0s = *(const float4*)(Arow0);
    const float4 a1s = *(const float4*)(Arow1);
    const float4 b0s = *(const float4*)(Wrow0);
    const float4 b1s = *(const float4*)(Wrow1);
    As[0][ak + 0][am] = a0s.x;
    As[0][ak + 1][am] = a0s.y;
    As[0][ak + 2][am] = a0s.z;
    As[0][ak + 3][am] = a0s.w;
    As[0][ak + 0][am + 64] = a1s.x;
    As[0][ak + 1][am + 64] = a1s.y;
    As[0][ak + 2][am + 64] = a1s.z;
    As[0][ak + 3][am + 64] = a1s.w;
    *(float4*)&Bs[0][bk][bn] = b0s;
    *(float4*)&Bs[0][bk + 8][bn] = b1s;
  }
  __syncthreads();

  for (int kt = 0; kt < ntiles; ++kt) {
    const int cur = kt & 1;
    float4 a0s, a1s, b0s, b1s;
    if (kt + 1 < ntiles) {
      const int k0 = (kt + 1) * BK;
      a0s = *(const float4*)(Arow0 + k0);
      a1s = *(const float4*)(Arow1 + k0);
      b0s = *(const float4*)(Wrow0 + (size_t)k0 * F);
      b1s = *(const float4*)(Wrow1 + (size_t)k0 * F);
    }

#pragma unroll
    for (int k = 0; k < BK; k += 2) {
      float a0[8], a1[8];
      *(float4*)&a0[0] = *(const float4*)&As[cur][k][ty * 8];
      *(float4*)&a0[4] = *(const float4*)&As[cur][k][ty * 8 + 4];
      *(float4*)&a1[0] = *(const float4*)&As[cur][k + 1][ty * 8];
      *(float4*)&a1[4] = *(const float4*)&As[cur][k + 1][ty * 8 + 4];
#pragma unroll
      for (int h = 0; h < 2; ++h) {  // column halves: cols h*64 + 4tx..+3
        float b0[4], b1[4];
        *(float4*)&b0[0] = *(const float4*)&Bs[cur][k][h * 64 + tx * 4];
        *(float4*)&b1[0] = *(const float4*)&Bs[cur][k + 1][h * 64 + tx * 4];
#pragma unroll
        for (int m = 0; m < 8; ++m)
#pragma unroll
          for (int n = 0; n < 4; ++n) {
            const float t0 = a0[m] + b0[n];  // v_add_f32 (2 cyc)
            const float t1 = a1[m] + b1[n];  // v_add_f32 (2 cyc)
            acc[m][h * 4 + n] = fmax3(acc[m][h * 4 + n], t0, t1);  // 2 cyc
          }
      }
    }

    if (kt + 1 < ntiles) {
      const int nxt = cur ^ 1;
      As[nxt][ak + 0][am] = a0s.x;
      As[nxt][ak + 1][am] = a0s.y;
      As[nxt][ak + 2][am] = a0s.z;
      As[nxt][ak + 3][am] = a0s.w;
      As[nxt][ak + 0][am + 64] = a1s.x;
      As[nxt][ak + 1][am + 64] = a1s.y;
      As[nxt][ak + 2][am + 64] = a1s.z;
      As[nxt][ak + 3][am + 64] = a1s.w;
      *(float4*)&Bs[nxt][bk][bn] = b0s;
      *(float4*)&Bs[nxt][bk + 8][bn] = b1s;
      __syncthreads();
    }
  }

  if (fuse) {
    const float4 bv0 = *(const float4*)(bias + col0 + tx * 4);
    const float4 bv1 = *(const float4*)(bias + col0 + 64 + tx * 4);
#pragma unroll
    for (int m = 0; m < 8; ++m) {
      float* orow = outf + (size_t)(row0 + ty * 8 + m) * F + col0 + tx * 4;
      float4 o0, o1;
      o0.x = fmaxf(acc[m][0], bv0.x);
      o0.y = fmaxf(acc[m][1], bv0.y);
      o0.z = fmaxf(acc[m][2], bv0.z);
      o0.w = fmaxf(acc[m][3], bv0.w);
      o1.x = fmaxf(acc[m][4], bv1.x);
      o1.y = fmaxf(acc[m][5], bv1.y);
      o1.z = fmaxf(acc[m][6], bv1.z);
      o1.w = fmaxf(acc[m][7], bv1.w);
      *(float4*)orow = o0;
      *(float4*)(orow + 64) = o1;
    }
  } else {
    _Float16* base = dsth + (size_t)blockIdx.z * totrows * F;
#pragma unroll
    for (int m = 0; m < 8; ++m) {
      _Float16* orow = base + (size_t)(row0 + ty * 8 + m) * F + col0 + tx * 4;
      h4 o0 = {(_Float16)acc[m][0], (_Float16)acc[m][1],
               (_Float16)acc[m][2], (_Float16)acc[m][3]};
      h4 o1 = {(_Float16)acc[m][4], (_Float16)acc[m][5],
               (_Float16)acc[m][6], (_Float16)acc[m][7]};
      *(h4*)orow = o0;
      *(h4*)(orow + 64) = o1;
    }
  }
}

// ---------------- combine: out = max(NP fp16 partials, bias) in f32 ----------------
template <int NP>
__global__ __launch_bounds__(256) void combineNh(const _Float16* __restrict__ p,
                                                 size_t plane,
                                                 const float* __restrict__ bias,
                                                 float* __restrict__ out) {
  const int i = blockIdx.x * 256 + threadIdx.x;  // h8 index
  h8 v = ((const h8*)p)[i];
  h2* vv = (h2*)&v;
#pragma unroll
  for (int q = 1; q < NP; ++q) {
    const h8 u = ((const h8*)(p + (size_t)q * plane))[i];
    const h2* uu = (const h2*)&u;
#pragma unroll
    for (int j = 0; j < 4; ++j) vv[j] = pk_max(vv[j], uu[j]);
  }
  const int nb = (i & (F / 8 - 1)) * 8;
  const v4f bb0 = *(const v4f*)(bias + nb);
  const v4f bb1 = *(const v4f*)(bias + nb + 4);
  float4* o4 = (float4*)(out + (size_t)i * 8);
  float4 o0, o1;
  o0.x = fmaxf((float)v[0], bb0.x);
  o0.y = fmaxf((float)v[1], bb0.y);
  o0.z = fmaxf((float)v[2], bb0.z);
  o0.w = fmaxf((float)v[3], bb0.w);
  o1.x = fmaxf((float)v[4], bb1.x);
  o1.y = fmaxf((float)v[5], bb1.y);
  o1.z = fmaxf((float)v[6], bb1.z);
  o1.w = fmaxf((float)v[7], bb1.w);
  o4[0] = o0;
  o4[1] = o1;
}

extern "C" void kernel_launch(void* const* d_in, const int* in_sizes, int n_in,
                              void* d_out, int out_size, void* d_ws, size_t ws_size,
                              hipStream_t stream) {
  const float* x = (const float*)d_in[0];
  const float* Wm = (const float*)d_in[1];
  const float* bias = (const float*)d_in[2];
  const float* gamma = (const float*)d_in[3];
  const float* beta = (const float*)d_in[4];
  float* out = (float*)d_out;

  const int Brows = in_sizes[0] / F;  // 4096
  const size_t plane = (size_t)Brows * F;

  float* xn = (float*)d_ws;                 // plane f32 (16 MB)
  _Float16* parts = (_Float16*)(xn + plane);  // 4 planes fp16 (32 MB)

  ln_kernel<<<Brows / 4, 256, 0, stream>>>(x, gamma, beta, xn);

  const size_t need4 = plane * sizeof(float) + 4 * plane * sizeof(_Float16);
  const size_t need1 = plane * sizeof(float);
  if (ws_size >= need4) {
    dim3 grid(F / BN, Brows / BM, 4);  // 1024 blocks = 4 blocks/CU
    trop_f<<<grid, 256, 0, stream>>>(xn, Wm, bias, parts, nullptr,
                                     (F / BK) / 4, Brows, 0);
    combineNh<4><<<(int)(plane / 2048), 256, 0, stream>>>(parts, plane, bias, out);
  } else if (ws_size >= need1) {
    dim3 grid(F / BN, Brows / BM, 1);
    trop_f<<<grid, 256, 0, stream>>>(xn, Wm, bias, nullptr, out, F / BK, Brows, 1);
  }
}